// Round 6
// baseline (143.507 us; speedup 1.0000x reference)
//
#include <hip/hip_runtime.h>

// LogisticRegressionRBF: out[k] = sigmoid( sum_n w[n]*exp(-||x_k - c_n||^2) + b )
// K=65536, N=4096, M=64. fp32 in/out.
//
// R6: branchless K-loop. R5's per-tile `if(__any(...))` (8 branches/chunk)
// fenced the scheduler into ~100-cyc dependency chains per tile. Now:
//   - MFMA C operand = loop-invariant p4 tuple (acc = dot + p, ZERO init adds)
//   - per tile: 2 MFMA + 3 max + 1 add(q) + 1 running-max  (no cmp/branch)
//   - ONE __any(rmax > TSKIP) after the loop gates a cold exact re-run of the
//     wave's whole slice (trigger ~4% of waves; test identical to R4/R5's
//     per-tile exact test -> correct for arbitrary inputs, error < 2^-28).
// Keeps: fragment-order cb direct from L2, ping-pong register prefetch,
// 2*log2e-scaled A, fused sigmoid, single main kernel.

#define KOBS 65536
#define NCENT 4096
#define MFEAT 64
#define BR 64                       // x-rows per block
#define BN 128                      // centers per chunk
#define NCHUNK (NCENT / BN)         // 32
#define KBLK (KOBS / BR)            // 1024

#define SCALE_A 2.8853900817779268f   // 2*log2(e)
#define QS      1.4426950408889634f   // log2(e)
#define TSKIP   -60.0f

typedef __attribute__((ext_vector_type(8))) short short8;
typedef __attribute__((ext_vector_type(4))) float float4v;
typedef __attribute__((ext_vector_type(2))) float float2v;

#if __has_builtin(__builtin_amdgcn_exp2f)
#define EXP2F(x) __builtin_amdgcn_exp2f(x)
#else
#define EXP2F(x) exp2f(x)
#endif

static __device__ inline short f2bf(float f) {
    unsigned int u = __float_as_uint(f);
    unsigned int r = (u + 0x7fffu + ((u >> 16) & 1u)) >> 16;
    return (short)r;
}

// Fused prep. Blocks [0,128): octet transpose xb fp32 -> cb bf16 in MFMA
// fragment order. Blocks [128,1152): hc2w[n] = { -log2e*||c_n||^2, w[n] }.
__global__ __launch_bounds__(256) void rbf_prep(
    const float* __restrict__ xb, const float* __restrict__ w,
    short* __restrict__ cb, float2v* __restrict__ hc2w) {
    const int bid = blockIdx.x;
    const int tid = threadIdx.x;
    if (bid < 128) {
        const int o    = bid * 256 + tid;        // octet index, [0, 32768)
        const int tile = o >> 7;
        const int r    = o & 127;
        const int p    = r >> 6;
        const int g    = (r >> 4) & 3;
        const int mm   = r & 15;
        const int row  = tile * 16 + mm;
        const int k0   = p * 32 + g * 8;
        float4v v0 = *(const float4v*)(xb + row * MFEAT + k0);
        float4v v1 = *(const float4v*)(xb + row * MFEAT + k0 + 4);
        short8 oct;
        #pragma unroll
        for (int j = 0; j < 4; ++j) { oct[j] = f2bf(v0[j]); oct[j + 4] = f2bf(v1[j]); }
        *(short8*)(cb + o * 8) = oct;
    } else {
        const int row  = (bid - 128) * 4 + (tid >> 6);
        const int lane = tid & 63;
        float v = xb[row * MFEAT + lane];
        float s = v * v;
        #pragma unroll
        for (int off = 32; off > 0; off >>= 1) s += __shfl_xor(s, off, 64);
        if (lane == 0) {
            float2v hw = {-QS * s, w[row]};
            hc2w[row] = hw;
        }
    }
}

__global__ __launch_bounds__(256, 4) void rbf_main(
    const float* __restrict__ x, const short* __restrict__ cb,
    const float2v* __restrict__ hc2w, const float* __restrict__ bptr,
    float* __restrict__ out) {
    __shared__ float x2s[BR];
    __shared__ float red[4 * BR];

    const int tid  = threadIdx.x;
    const int wave = tid >> 6;
    const int lane = tid & 63;
    const int m    = lane & 15;
    const int g    = lane >> 4;
    const int r0   = (int)blockIdx.x * BR;

    // ---- A fragments for all 64 rows (4 row-groups), scaled by 2*log2e ----
    short8 af[4][2];
    float  ssr[4];
    #pragma unroll
    for (int rg = 0; rg < 4; ++rg) {
        const float* xr = x + (r0 + rg * 16 + m) * MFEAT + g * 8;
        float4v a0 = *(const float4v*)(xr);
        float4v a1 = *(const float4v*)(xr + 4);
        float4v a2 = *(const float4v*)(xr + 32);
        float4v a3 = *(const float4v*)(xr + 36);
        float ss = 0.0f;
        #pragma unroll
        for (int i = 0; i < 4; ++i) {
            af[rg][0][i]     = f2bf(SCALE_A * a0[i]);  ss = fmaf(a0[i], a0[i], ss);
            af[rg][0][i + 4] = f2bf(SCALE_A * a1[i]);  ss = fmaf(a1[i], a1[i], ss);
            af[rg][1][i]     = f2bf(SCALE_A * a2[i]);  ss = fmaf(a2[i], a2[i], ss);
            af[rg][1][i + 4] = f2bf(SCALE_A * a3[i]);  ss = fmaf(a3[i], a3[i], ss);
        }
        ss += __shfl_xor(ss, 16, 64);
        ss += __shfl_xor(ss, 32, 64);
        ssr[rg] = ss;
    }
    if (g == 0) {
        #pragma unroll
        for (int rg = 0; rg < 4; ++rg) x2s[rg * 16 + m] = ssr[rg];
    }
    __syncthreads();

    // p tuples (C-init): p = -log2e * x2 for C-layout row rg*16 + g*4 + i
    float4v p4v[4];
    #pragma unroll
    for (int rg = 0; rg < 4; ++rg)
        #pragma unroll
        for (int i = 0; i < 4; ++i) p4v[rg][i] = -QS * x2s[rg * 16 + g * 4 + i];

    // ---- B fragment base for this wave/lane (fragment-order cb) ----
    const char* cbb = (const char*)cb + wave * 4096 + lane * 16;
    const float2v* hwp = hc2w + wave * 32 + m;

    short8  pb0[2][2], pb1[2][2];
    float2v phw[2][2];

    #define LOADT(c, tt, s) do {                                             \
        pb0[s][tt] = *(const short8*)(cbb + (c) * 16384 + (tt) * 2048);      \
        pb1[s][tt] = *(const short8*)(cbb + (c) * 16384 + (tt) * 2048 + 1024);\
        phw[s][tt] = hwp[(c) * 128 + (tt) * 16];                             \
    } while (0)

    LOADT(0, 0, 0);
    LOADT(0, 1, 0);

    float rmax = -3.0e38f;   // running max of log2(phi) over this wave's slice

    #pragma unroll 2
    for (int c = 0; c < NCHUNK; ++c) {
        const int cur = c & 1, nxt = cur ^ 1;
        if (c + 1 < NCHUNK) {
            LOADT(c + 1, 0, nxt);
            LOADT(c + 1, 1, nxt);
        }
        #pragma unroll
        for (int tt2 = 0; tt2 < 2; ++tt2) {
            short8 b0 = pb0[cur][tt2];
            short8 b1 = pb1[cur][tt2];
            float q  = phw[cur][tt2].x;
            #pragma unroll
            for (int rg = 0; rg < 4; ++rg) {
                float4v acc = __builtin_amdgcn_mfma_f32_16x16x32_bf16(
                    af[rg][0], b0, p4v[rg], 0, 0, 0);        // acc = dot + p
                acc = __builtin_amdgcn_mfma_f32_16x16x32_bf16(
                    af[rg][1], b1, acc, 0, 0, 0);
                float mx = fmaxf(fmaxf(acc[0], acc[1]), fmaxf(acc[2], acc[3]));
                rmax = fmaxf(rmax, mx + q);
            }
        }
    }

    // ---- cold slow path: exact re-run if any tile might contribute ----
    float accw[4][4];
    #pragma unroll
    for (int rg = 0; rg < 4; ++rg)
        #pragma unroll
        for (int i = 0; i < 4; ++i) accw[rg][i] = 0.0f;

    if (__any(rmax > TSKIP)) {
        for (int c = 0; c < NCHUNK; ++c) {
            #pragma unroll
            for (int tt2 = 0; tt2 < 2; ++tt2) {
                short8 b0 = *(const short8*)(cbb + c * 16384 + tt2 * 2048);
                short8 b1 = *(const short8*)(cbb + c * 16384 + tt2 * 2048 + 1024);
                float2v hw = hwp[c * 128 + tt2 * 16];
                #pragma unroll
                for (int rg = 0; rg < 4; ++rg) {
                    float4v acc = __builtin_amdgcn_mfma_f32_16x16x32_bf16(
                        af[rg][0], b0, p4v[rg], 0, 0, 0);
                    acc = __builtin_amdgcn_mfma_f32_16x16x32_bf16(
                        af[rg][1], b1, acc, 0, 0, 0);
                    float mx = fmaxf(fmaxf(acc[0], acc[1]), fmaxf(acc[2], acc[3]));
                    if (__any(mx + hw.x > TSKIP)) {
                        #pragma unroll
                        for (int i = 0; i < 4; ++i) {
                            float phi = EXP2F(acc[i] + hw.x);
                            accw[rg][i] = fmaf(hw.y, phi, accw[rg][i]);
                        }
                    }
                }
            }
        }
    }

    // ---- reduce over 16 n-lanes, combine 4 waves via LDS, sigmoid, store ----
    #pragma unroll
    for (int rg = 0; rg < 4; ++rg)
        #pragma unroll
        for (int i = 0; i < 4; ++i) {
            float v = accw[rg][i];
            v += __shfl_xor(v, 1, 64);
            v += __shfl_xor(v, 2, 64);
            v += __shfl_xor(v, 4, 64);
            v += __shfl_xor(v, 8, 64);
            accw[rg][i] = v;
        }
    if (m == 0) {
        #pragma unroll
        for (int rg = 0; rg < 4; ++rg)
            #pragma unroll
            for (int i = 0; i < 4; ++i)
                red[wave * BR + rg * 16 + g * 4 + i] = accw[rg][i];
    }
    __syncthreads();
    if (tid < BR) {
        float z = red[tid] + red[BR + tid] + red[2 * BR + tid] + red[3 * BR + tid]
                + bptr[0];
        out[r0 + tid] = 1.0f / (1.0f + EXP2F(-QS * z));
    }
}

extern "C" void kernel_launch(void* const* d_in, const int* in_sizes, int n_in,
                              void* d_out, int out_size, void* d_ws, size_t ws_size,
                              hipStream_t stream) {
    const float* x  = (const float*)d_in[0];   // [K, M]
    const float* xb = (const float*)d_in[1];   // [N, M]
    const float* w  = (const float*)d_in[2];   // [1, N]
    const float* b  = (const float*)d_in[3];   // [1]
    float* out = (float*)d_out;                // [K]

    short*   cb   = (short*)d_ws;                                 // 512 KB
    float2v* hc2w = (float2v*)((char*)d_ws + NCENT * MFEAT * 2);  // 32 KB

    rbf_prep<<<128 + NCENT / 4, 256, 0, stream>>>(xb, w, cb, hc2w);
    rbf_main<<<KBLK, 256, 0, stream>>>(x, cb, hc2w, b, out);
}

// Round 7
// 105.331 us; speedup vs baseline: 1.3624x; 1.3624x over previous
//
#include <hip/hip_runtime.h>

// LogisticRegressionRBF: out[k] = sigmoid( sum_n w[n]*exp(-||x_k - c_n||^2) + b )
// K=65536, N=4096, M=64. fp32 in/out.
//
// R7: R5 structure (single K-loop, direct-from-L2 fragment loads, ping-pong
// register prefetch, per-group underflow skip) + R6's C-operand init WITHOUT
// the duplicated slow-path loop that caused R6's scratch spills (WRITE_SIZE
// 0.25->17.8 MB = smoking gun; MFMA-busy time was identical, so the deferred
// path never ran -- only the spills cost 32 us).
//   - acc = mfma(af, b, p4v): C initialized with p = -log2e*x2, zero init adds
//   - rg-PAIR grouping: 4 MFMAs -> one 8-reg max -> ONE __any branch
//     (4 branches/chunk vs R5's 8, only +8 live VGPRs vs R6's +spills)
//   - tq = TSKIP - q precomputed at prefetch: hot test is just mx > tq
// Skip test exactness: group contributes only if some element of acc+q =
// log2(phi) > -60; skipped group's total contribution < 512*|w|*2^-60 -> far
// below fp32 resolution of the result for ANY input (adaptive fallback).

#define KOBS 65536
#define NCENT 4096
#define MFEAT 64
#define BR 64                       // x-rows per block
#define BN 128                      // centers per chunk
#define NCHUNK (NCENT / BN)         // 32
#define KBLK (KOBS / BR)            // 1024

#define SCALE_A 2.8853900817779268f   // 2*log2(e)
#define QS      1.4426950408889634f   // log2(e)
#define TSKIP   -60.0f

typedef __attribute__((ext_vector_type(8))) short short8;
typedef __attribute__((ext_vector_type(4))) float float4v;
typedef __attribute__((ext_vector_type(2))) float float2v;

#if __has_builtin(__builtin_amdgcn_exp2f)
#define EXP2F(x) __builtin_amdgcn_exp2f(x)
#else
#define EXP2F(x) exp2f(x)
#endif

static __device__ inline short f2bf(float f) {
    unsigned int u = __float_as_uint(f);
    unsigned int r = (u + 0x7fffu + ((u >> 16) & 1u)) >> 16;
    return (short)r;
}

// Fused prep. Blocks [0,128): octet transpose xb fp32 -> cb bf16 in MFMA
// fragment order. Blocks [128,1152): hc2w[n] = { -log2e*||c_n||^2, w[n] }.
__global__ __launch_bounds__(256) void rbf_prep(
    const float* __restrict__ xb, const float* __restrict__ w,
    short* __restrict__ cb, float2v* __restrict__ hc2w) {
    const int bid = blockIdx.x;
    const int tid = threadIdx.x;
    if (bid < 128) {
        const int o    = bid * 256 + tid;        // octet index, [0, 32768)
        const int tile = o >> 7;
        const int r    = o & 127;
        const int p    = r >> 6;
        const int g    = (r >> 4) & 3;
        const int mm   = r & 15;
        const int row  = tile * 16 + mm;
        const int k0   = p * 32 + g * 8;
        float4v v0 = *(const float4v*)(xb + row * MFEAT + k0);
        float4v v1 = *(const float4v*)(xb + row * MFEAT + k0 + 4);
        short8 oct;
        #pragma unroll
        for (int j = 0; j < 4; ++j) { oct[j] = f2bf(v0[j]); oct[j + 4] = f2bf(v1[j]); }
        *(short8*)(cb + o * 8) = oct;
    } else {
        const int row  = (bid - 128) * 4 + (tid >> 6);
        const int lane = tid & 63;
        float v = xb[row * MFEAT + lane];
        float s = v * v;
        #pragma unroll
        for (int off = 32; off > 0; off >>= 1) s += __shfl_xor(s, off, 64);
        if (lane == 0) {
            float2v hw = {-QS * s, w[row]};
            hc2w[row] = hw;
        }
    }
}

__global__ __launch_bounds__(256, 4) void rbf_main(
    const float* __restrict__ x, const short* __restrict__ cb,
    const float2v* __restrict__ hc2w, const float* __restrict__ bptr,
    float* __restrict__ out) {
    __shared__ float x2s[BR];
    __shared__ float red[4 * BR];

    const int tid  = threadIdx.x;
    const int wave = tid >> 6;
    const int lane = tid & 63;
    const int m    = lane & 15;
    const int g    = lane >> 4;
    const int r0   = (int)blockIdx.x * BR;

    // ---- A fragments for all 64 rows (4 row-groups), scaled by 2*log2e ----
    short8 af[4][2];
    float  ssr[4];
    #pragma unroll
    for (int rg = 0; rg < 4; ++rg) {
        const float* xr = x + (r0 + rg * 16 + m) * MFEAT + g * 8;
        float4v a0 = *(const float4v*)(xr);
        float4v a1 = *(const float4v*)(xr + 4);
        float4v a2 = *(const float4v*)(xr + 32);
        float4v a3 = *(const float4v*)(xr + 36);
        float ss = 0.0f;
        #pragma unroll
        for (int i = 0; i < 4; ++i) {
            af[rg][0][i]     = f2bf(SCALE_A * a0[i]);  ss = fmaf(a0[i], a0[i], ss);
            af[rg][0][i + 4] = f2bf(SCALE_A * a1[i]);  ss = fmaf(a1[i], a1[i], ss);
            af[rg][1][i]     = f2bf(SCALE_A * a2[i]);  ss = fmaf(a2[i], a2[i], ss);
            af[rg][1][i + 4] = f2bf(SCALE_A * a3[i]);  ss = fmaf(a3[i], a3[i], ss);
        }
        ss += __shfl_xor(ss, 16, 64);
        ss += __shfl_xor(ss, 32, 64);
        ssr[rg] = ss;
    }
    if (g == 0) {
        #pragma unroll
        for (int rg = 0; rg < 4; ++rg) x2s[rg * 16 + m] = ssr[rg];
    }
    __syncthreads();

    // C-init tuples: p = -log2e * x2 for C-layout row rg*16 + g*4 + i
    float4v p4v[4];
    #pragma unroll
    for (int rg = 0; rg < 4; ++rg)
        #pragma unroll
        for (int i = 0; i < 4; ++i) p4v[rg][i] = -QS * x2s[rg * 16 + g * 4 + i];

    float accw[4][4];
    #pragma unroll
    for (int rg = 0; rg < 4; ++rg)
        #pragma unroll
        for (int i = 0; i < 4; ++i) accw[rg][i] = 0.0f;

    // ---- B fragment base for this wave/lane (fragment-order cb) ----
    const char* cbb = (const char*)cb + wave * 4096 + lane * 16;
    const float2v* hwp = hc2w + wave * 32 + m;

    // ping-pong prefetch: B frags + {tq = TSKIP - q, w}
    short8  pb0[2][2], pb1[2][2];
    float2v phw[2][2];

    #define LOADT(c, tt, s) do {                                              \
        pb0[s][tt] = *(const short8*)(cbb + (c) * 16384 + (tt) * 2048);       \
        pb1[s][tt] = *(const short8*)(cbb + (c) * 16384 + (tt) * 2048 + 1024);\
        float2v hw_ = hwp[(c) * 128 + (tt) * 16];                             \
        hw_.x = TSKIP - hw_.x;                                                \
        phw[s][tt] = hw_;                                                     \
    } while (0)

    LOADT(0, 0, 0);
    LOADT(0, 1, 0);

    #pragma unroll 2
    for (int c = 0; c < NCHUNK; ++c) {
        const int cur = c & 1, nxt = cur ^ 1;
        if (c + 1 < NCHUNK) {
            LOADT(c + 1, 0, nxt);
            LOADT(c + 1, 1, nxt);
        }
        #pragma unroll
        for (int tt2 = 0; tt2 < 2; ++tt2) {
            short8 b0 = pb0[cur][tt2];
            short8 b1 = pb1[cur][tt2];
            float  tq = phw[cur][tt2].x;
            float  wv = phw[cur][tt2].y;
            #pragma unroll
            for (int rp = 0; rp < 2; ++rp) {          // rg pairs {0,1},{2,3}
                const int rg0 = rp * 2, rg1 = rp * 2 + 1;
                float4v a0 = __builtin_amdgcn_mfma_f32_16x16x32_bf16(
                    af[rg0][0], b0, p4v[rg0], 0, 0, 0);   // acc = dot + p
                a0 = __builtin_amdgcn_mfma_f32_16x16x32_bf16(
                    af[rg0][1], b1, a0, 0, 0, 0);
                float4v a1 = __builtin_amdgcn_mfma_f32_16x16x32_bf16(
                    af[rg1][0], b0, p4v[rg1], 0, 0, 0);
                a1 = __builtin_amdgcn_mfma_f32_16x16x32_bf16(
                    af[rg1][1], b1, a1, 0, 0, 0);
                float mx = fmaxf(
                    fmaxf(fmaxf(a0[0], a0[1]), fmaxf(a0[2], a0[3])),
                    fmaxf(fmaxf(a1[0], a1[1]), fmaxf(a1[2], a1[3])));
                if (__any(mx > tq)) {                 // rare: ~1e-4 of groups
                    float q = TSKIP - tq;
                    #pragma unroll
                    for (int i = 0; i < 4; ++i) {
                        accw[rg0][i] = fmaf(wv, EXP2F(a0[i] + q), accw[rg0][i]);
                        accw[rg1][i] = fmaf(wv, EXP2F(a1[i] + q), accw[rg1][i]);
                    }
                }
            }
        }
    }

    // ---- reduce over 16 n-lanes, combine 4 waves via LDS, sigmoid, store ----
    #pragma unroll
    for (int rg = 0; rg < 4; ++rg)
        #pragma unroll
        for (int i = 0; i < 4; ++i) {
            float v = accw[rg][i];
            v += __shfl_xor(v, 1, 64);
            v += __shfl_xor(v, 2, 64);
            v += __shfl_xor(v, 4, 64);
            v += __shfl_xor(v, 8, 64);
            accw[rg][i] = v;
        }
    if (m == 0) {
        #pragma unroll
        for (int rg = 0; rg < 4; ++rg)
            #pragma unroll
            for (int i = 0; i < 4; ++i)
                red[wave * BR + rg * 16 + g * 4 + i] = accw[rg][i];
    }
    __syncthreads();
    if (tid < BR) {
        float z = red[tid] + red[BR + tid] + red[2 * BR + tid] + red[3 * BR + tid]
                + bptr[0];
        out[r0 + tid] = 1.0f / (1.0f + EXP2F(-QS * z));
    }
}

extern "C" void kernel_launch(void* const* d_in, const int* in_sizes, int n_in,
                              void* d_out, int out_size, void* d_ws, size_t ws_size,
                              hipStream_t stream) {
    const float* x  = (const float*)d_in[0];   // [K, M]
    const float* xb = (const float*)d_in[1];   // [N, M]
    const float* w  = (const float*)d_in[2];   // [1, N]
    const float* b  = (const float*)d_in[3];   // [1]
    float* out = (float*)d_out;                // [K]

    short*   cb   = (short*)d_ws;                                 // 512 KB
    float2v* hc2w = (float2v*)((char*)d_ws + NCENT * MFEAT * 2);  // 32 KB

    rbf_prep<<<128 + NCENT / 4, 256, 0, stream>>>(xb, w, cb, hc2w);
    rbf_main<<<KBLK, 256, 0, stream>>>(x, cb, hc2w, b, out);
}